// Round 7
// baseline (474.520 us; speedup 1.0000x reference)
//
#include <hip/hip_runtime.h>
#include <hip/hip_bf16.h>

typedef unsigned short u16;
typedef unsigned short u16x8 __attribute__((ext_vector_type(8)));
typedef __bf16 bf16x8 __attribute__((ext_vector_type(8)));
typedef float f32x4 __attribute__((ext_vector_type(4)));

#define LRS 0.2f

__device__ __forceinline__ u16 f2b(float f) {
  __hip_bfloat16 h = __float2bfloat16(f);
  return __builtin_bit_cast(u16, h);
}

// ---------------------------------------------------------------------------
// R rows (LDS f32, stride K) x W[O][K] f32 -> y[R][O]; KSEG lanes per K.
// ---------------------------------------------------------------------------
template<int K, int O, int KSEG, int R>
__device__ __forceinline__ void gemm_rowsR(const float* xr, const float* W, const float* bias,
                                           float* yl, float* yg, int ygstride) {
  constexpr int KPT = K / KSEG;
  constexpr int OPP = 256 / KSEG;
  const int t = threadIdx.x;
  const int ks = t % KSEG;
  const int oi = t / KSEG;
#pragma unroll
  for (int pass = 0; pass < O / OPP; ++pass) {
    const int o = pass * OPP + oi;
    float a[R];
#pragma unroll
    for (int r = 0; r < R; ++r) a[r] = 0.0f;
    const float* wp = W + (size_t)o * K + ks * KPT;
    const float* xb = xr + ks * KPT;
#pragma unroll 4
    for (int kc = 0; kc < KPT; kc += 4) {
      f32x4 w4 = *(const f32x4*)(wp + kc);
#pragma unroll
      for (int r = 0; r < R; ++r) {
        f32x4 x = *(const f32x4*)(xb + r * K + kc);
#pragma unroll
        for (int j = 0; j < 4; ++j) a[r] += x[j] * w4[j];
      }
    }
#pragma unroll
    for (int d = 1; d < KSEG; d <<= 1)
#pragma unroll
      for (int r = 0; r < R; ++r) a[r] += __shfl_xor(a[r], d, 64);
    if (ks == 0) {
      float bv = bias ? bias[o] : 0.0f;
#pragma unroll
      for (int r = 0; r < R; ++r) {
        float v = a[r] + bv;
        if (yl) yl[r * O + o] = v;
        if (yg) yg[(size_t)r * ygstride + o] = v;
      }
    }
  }
}

// ---------------------------------------------------------------------------
// W1: fold weights. Mfull[hf][c]; vb[c][16] bf16 (score B-matrix, h>=8 zero);
//     cbe; sconst.
// ---------------------------------------------------------------------------
__global__ __launch_bounds__(256) void kW1(const float* We_w, const float* We_b, const float* attn,
                                           const float* We2_w, const float* We2_b,
                                           const float* edge_w, const float* edge_b,
                                           float* Mfull, u16* vb, float* cbe, float* sconst) {
  int gid = blockIdx.x * 256 + threadIdx.x;
  if (gid < 16384) {
    int hf = gid >> 7, c = gid & 127;
    int h = hf >> 4, fo = hf & 15;
    float s = 0;
    for (int e = 0; e < 16; ++e)
      s += edge_w[fo * 176 + e] * We2_w[(h * 16 + e) * 128 + c];
    Mfull[hf * 128 + c] = s;
  } else if (gid < 16384 + 2048) {
    int idx = gid - 16384;
    int c = idx >> 4, hc = idx & 15;
    float s = 0;
    if (hc < 8)
      for (int e = 0; e < 16; ++e)
        s += We_w[(hc * 16 + e) * 128 + c] * attn[128 + e];
    vb[c * 16 + hc] = f2b(s);
  } else if (gid < 18432 + 128) {
    int hf = gid - 18432;
    int h = hf >> 4, fo = hf & 15;
    float s = edge_b[fo];
    for (int e = 0; e < 16; ++e)
      s += We2_b[h * 16 + e] * edge_w[fo * 176 + e];
    cbe[hf] = s;
  } else if (gid < 18560 + 8) {
    int h = gid - 18560;
    float s = 0;
    for (int e = 0; e < 16; ++e)
      s += We_b[h * 16 + e] * attn[128 + e];
    sconst[h] = s;
  }
}

// W2: G[o][c] = sum_k oute_w[o,k]*Mfull[k][c], stored bf16 row-major (o,c)
__global__ __launch_bounds__(256) void kW2(const float* oute_w, const float* Mfull, u16* Gb) {
  int gid = blockIdx.x * 256 + threadIdx.x;
  int o = gid >> 7, c = gid & 127;
  float s = 0;
  for (int k = 0; k < 128; ++k)
    s += oute_w[o * 128 + k] * Mfull[k * 128 + c];
  Gb[o * 128 + c] = f2b(s);
}

// ---------------------------------------------------------------------------
// N1: per 2 node-rows (grid 512): npj, dpj, node_wh, srow, scol
// ---------------------------------------------------------------------------
__global__ __launch_bounds__(256) void kN1(const float* node, const float* diff,
                                           const float* Wn_w, const float* Wn_b,
                                           const float* Wd_w, const float* Wd_b,
                                           const float* Wh_w, const float* Wh_b,
                                           const float* attn, const float* sconst,
                                           float* npj_g, float* nwh_g,
                                           float* srow_g, float* scol_g) {
  __shared__ float nrow[2 * 512], npjl[2 * 512], drow[2 * 128], dpjl[2 * 128];
  const int t = threadIdx.x;
  const int r0 = blockIdx.x * 2;
  *(f32x4*)&nrow[t * 4] = *(const f32x4*)(node + (size_t)r0 * 512 + t * 4);
  if (t < 64) *(f32x4*)&drow[t * 4] = *(const f32x4*)(diff + (size_t)r0 * 128 + t * 4);
  __syncthreads();
  gemm_rowsR<512, 512, 4, 2>(nrow, Wn_w, Wn_b, npjl, npj_g + (size_t)r0 * 512, 512);
  gemm_rowsR<128, 128, 4, 2>(drow, Wd_w, Wd_b, dpjl, nullptr, 0);
  __syncthreads();
  {
    int d = t & 63, hh = t >> 6;
#pragma unroll
    for (int hi = 0; hi < 2; ++hi) {
      int h = hh + hi * 4;
      float wb = Wh_b[d];
      float acc[2] = {wb, wb};
      for (int k = 0; k < 64; ++k) {
        float w = Wh_w[d * 64 + k];
#pragma unroll
        for (int r = 0; r < 2; ++r) acc[r] += npjl[r * 512 + h * 64 + k] * w;
      }
#pragma unroll
      for (int r = 0; r < 2; ++r) nwh_g[(size_t)(r0 + r) * 512 + h * 64 + d] = acc[r];
    }
  }
  if (t < 16) {
    int r = t >> 3, h = t & 7;
    float shi = 0, shj = 0, sdi = 0, sdj = 0;
    for (int d = 0; d < 64; ++d) {
      float x = npjl[r * 512 + h * 64 + d];
      shi += x * attn[d];
      shj += x * attn[64 + d];
    }
    for (int e = 0; e < 16; ++e) {
      float x = dpjl[r * 128 + h * 16 + e];
      sdi += x * attn[144 + e];
      sdj += x * attn[160 + e];
    }
    srow_g[(r0 + r) * 8 + h] = shi + sdi + sconst[h];
    scol_g[(r0 + r) * 8 + h] = shj + sdj;
  }
}

// ---------------------------------------------------------------------------
// A: per (b,l) block (grid 1024).
// Phase S: stage 64-row edge tiles -> LDS bf16 swizzled (+optionally mirror to
// ws cache for kE), 4 MFMAs per tile vs vb -> se. Then softmax, agg, nnp.
// ---------------------------------------------------------------------------
__global__ __launch_bounds__(256) void kA(const float* edge, const float* npj, const float* nwh,
                                          const float* srow, const float* scol,
                                          const u16* vb, float* nnp, u16* abf) {
  __shared__ u16 At[8192];              // 16 KB: 64x128 bf16 swizzled
  __shared__ float sm[4608];            // scores [512][9]
  __shared__ float part[2][512];
  __shared__ float red[256];
  __shared__ float mxh8[8], inv8[8];
  const int bl = blockIdx.x;
  const int b = bl >> 9, l = bl & 511;
  const int t = threadIdx.x;
  const int lane = t & 63, w = t >> 6;
  const int colL = lane & 15, kg = lane >> 4;
  const int h = t & 7, seg = t >> 3;
  const int arow = t >> 2, aseg = t & 3;

  // B-fragments for score MFMA: B[k=c][col=h] = vb[c][h]
  bf16x8 bfr[4];
#pragma unroll
  for (int ks = 0; ks < 4; ++ks) {
    u16x8 u;
#pragma unroll
    for (int j = 0; j < 8; ++j) u[j] = vb[(ks * 32 + kg * 8 + j) * 16 + colL];
    bfr[ks] = __builtin_bit_cast(bf16x8, u);
  }

  // ---- phase S ----
  for (int tl = 0; tl < 8; ++tl) {
    {
      const float* p = edge + ((size_t)bl * 512 + tl * 64 + arow) * 128 + aseg * 32;
      f32x4 v[8];
#pragma unroll
      for (int q = 0; q < 8; ++q) v[q] = *(const f32x4*)(p + q * 4);
      u16* dst = abf ? abf + ((size_t)bl * 8 + tl) * 8192 : nullptr;
#pragma unroll
      for (int jj = 0; jj < 4; ++jj) {
        u16x8 a8;
#pragma unroll
        for (int j2 = 0; j2 < 4; ++j2) {
          a8[j2]     = f2b(v[2 * jj][j2]);
          a8[4 + j2] = f2b(v[2 * jj + 1][j2]);
        }
        int cu = aseg * 4 + jj;
        int su = arow * 16 + (cu ^ (arow & 7));
        *(u16x8*)(At + su * 8) = a8;
        if (dst) *(u16x8*)(dst + su * 8) = a8;
      }
    }
    __syncthreads();
    // MFMA: wave w covers rows tl*64 + w*16 .. +15
    f32x4 acc = {0, 0, 0, 0};
#pragma unroll
    for (int ks = 0; ks < 4; ++ks) {
      int cu = ks * 4 + kg;
      int lrow = w * 16 + colL;
      bf16x8 af = *(bf16x8*)(At + (lrow * 16 + (cu ^ (lrow & 7))) * 8);
      acc = __builtin_amdgcn_mfma_f32_16x16x32_bf16(af, bfr[ks], acc, 0, 0, 0);
    }
    if (colL < 8) {
#pragma unroll
      for (int r = 0; r < 4; ++r) {
        int m = tl * 64 + w * 16 + kg * 4 + r;
        sm[m * 9 + colL] = acc[r];
      }
    }
    __syncthreads();
  }

  // ---- softmax pass 1 ----
  const float srh2 = srow[(size_t)bl * 8 + h];
  float mx = -__builtin_inff();
#pragma unroll 4
  for (int i = 0; i < 16; ++i) {
    int m = seg * 16 + i;
    float sv = sm[m * 9 + h] + srh2 + scol[((size_t)b * 512 + m) * 8 + h];
    sv = (m == l) ? -__builtin_inff() : (sv >= 0.0f ? sv : LRS * sv);
    sm[m * 9 + h] = sv;
    mx = fmaxf(mx, sv);
  }
  red[t] = mx;
  __syncthreads();
  if (t < 8) {
    float m2 = -__builtin_inff();
    for (int sg = 0; sg < 32; ++sg) m2 = fmaxf(m2, red[sg * 8 + t]);
    mxh8[t] = m2;
  }
  __syncthreads();
  float mh = mxh8[h];
  float smv = 0;
#pragma unroll 4
  for (int i = 0; i < 16; ++i) {
    int m = seg * 16 + i;
    float p = __expf(sm[m * 9 + h] - mh);
    sm[m * 9 + h] = p;
    smv += p;
  }
  red[t] = smv;
  __syncthreads();
  if (t < 8) {
    float s2 = 0;
    for (int sg = 0; sg < 32; ++sg) s2 += red[sg * 8 + t];
    inv8[t] = 1.0f / s2;
  }
  __syncthreads();
  // ---- agg ----
  const int half = t >> 7, oq = t & 127;
  const int o4 = oq * 4, hh = oq >> 4;
  f32x4 acc4a = {0, 0, 0, 0}, acc4b = {0, 0, 0, 0};
  const float* nb = nwh + (size_t)b * 512 * 512;
  for (int m = half * 256; m < half * 256 + 256; m += 2) {
    acc4a += sm[m * 9 + hh]       * *(const f32x4*)(nb + (size_t)m * 512 + o4);
    acc4b += sm[(m + 1) * 9 + hh] * *(const f32x4*)(nb + (size_t)(m + 1) * 512 + o4);
  }
  *(f32x4*)&part[half][o4] = acc4a + acc4b;
  __syncthreads();
  if (t < 128) {
    int ob = t * 4, h2 = t >> 4;
    f32x4 s0 = *(f32x4*)&part[0][ob];
    f32x4 s1 = *(f32x4*)&part[1][ob];
    f32x4 np4 = *(const f32x4*)(npj + (size_t)bl * 512 + ob);
    float iv = inv8[h2];
    f32x4 o;
#pragma unroll
    for (int j = 0; j < 4; ++j) {
      float a = (s0[j] + s1[j]) * iv;
      a = a >= 0.0f ? a : LRS * a;
      o[j] = np4[j] + a;
    }
    *(f32x4*)(nnp + (size_t)bl * 512 + ob) = o;
  }
}

// ---------------------------------------------------------------------------
// N234 (fused, 2 rows/block, grid 512): nnp -> out0 -> np2/dp2 -> R -> Pl/Pm
// ---------------------------------------------------------------------------
__global__ __launch_bounds__(256) void kN234(const float* nnp, const float* diff,
                                             const float* outn_w, const float* outn_b,
                                             const float* Wn2_w, const float* Wn2_b,
                                             const float* Wd2_w, const float* Wd2_b,
                                             const float* edge_w, const float* cbe,
                                             const float* oute_w, const float* oute_b,
                                             float* out0, float* Pl, float* Pm) {
  __shared__ float xr[2 * 512], o0l[2 * 512], np2l[2 * 512], dr[2 * 128], dp2l[2 * 128];
  __shared__ float Rls[2 * 128], Rms[2 * 128];
  const int t = threadIdx.x;
  const int r0 = blockIdx.x * 2;
  *(f32x4*)&xr[t * 4] = *(const f32x4*)(nnp + (size_t)r0 * 512 + t * 4);
  if (t < 64) *(f32x4*)&dr[t * 4] = *(const f32x4*)(diff + (size_t)r0 * 128 + t * 4);
  __syncthreads();
  gemm_rowsR<512, 512, 4, 2>(xr, outn_w, outn_b, o0l, out0 + (size_t)r0 * 512, 512);
  gemm_rowsR<128, 128, 4, 2>(dr, Wd2_w, Wd2_b, dp2l, nullptr, 0);
  __syncthreads();
  gemm_rowsR<512, 512, 4, 2>(o0l, Wn2_w, Wn2_b, np2l, nullptr, 0);
  __syncthreads();
  {
    int hf = t & 127, which = t >> 7;
    int h = hf >> 4, fo = hf & 15;
    const float* wh = edge_w + fo * 176 + 16 + which * 64;   // W_hi / W_hj
    const float* wd = edge_w + fo * 176 + 144 + which * 16;  // W_di / W_dj
    float add = which ? 0.0f : cbe[hf];
    float* dst = which ? Rms : Rls;
#pragma unroll
    for (int r = 0; r < 2; ++r) {
      float a = add;
      for (int d = 0; d < 64; ++d) a += np2l[r * 512 + h * 64 + d] * wh[d];
      for (int e = 0; e < 16; ++e) a += dp2l[r * 128 + h * 16 + e] * wd[e];
      dst[r * 128 + hf] = a;
    }
  }
  __syncthreads();
  gemm_rowsR<128, 128, 4, 2>(Rls, oute_w, oute_b, nullptr, Pl + (size_t)r0 * 128, 128);
  gemm_rowsR<128, 128, 4, 2>(Rms, oute_w, nullptr, nullptr, Pm + (size_t)r0 * 128, 128);
}

// ---------------------------------------------------------------------------
// Ec: cached-bf16 edge GEMM. A tiles come pre-swizzled from ws (linear copy).
// ---------------------------------------------------------------------------
__global__ __launch_bounds__(256) void kEc(const u16* Abf, const u16* Gb,
                                           const float* Pl, const float* Pm, float* oute) {
  __shared__ u16 Gt[16384];   // 32 KB
  __shared__ u16 At[8192];    // 16 KB
  const int tile = blockIdx.x;
  const int bl = tile >> 2;
  const int b = bl >> 9;
  const int q0 = (tile & 3) * 128;
  const int t = threadIdx.x, lane = t & 63, w = t >> 6;
#pragma unroll
  for (int i2 = 0; i2 < 8; ++i2) {
    int u = i2 * 256 + t;
    int row = u >> 4, cu = u & 15;
    *(u16x8*)(Gt + (row * 16 + (cu ^ (row & 7))) * 8) = *(const u16x8*)(Gb + u * 8);
  }
  const int wr = w >> 1, wc = w & 1;
  const int colL = lane & 15, kg = lane >> 4;
  const float* plp = Pl + (size_t)bl * 128;
  f32x4 plv4[4];
#pragma unroll
  for (int n = 0; n < 4; ++n) plv4[n] = *(const f32x4*)(plp + wc * 64 + n * 16 + kg * 4);

  for (int sub = 0; sub < 2; ++sub) {
    const int r0 = q0 + sub * 64;
    const int gs = (tile & 3) * 2 + sub;
    const u16* src = Abf + ((size_t)bl * 8 + gs) * 8192;
    // linear image copy: LDS layout == ws layout
#pragma unroll
    for (int q = 0; q < 4; ++q)
      *(u16x8*)(At + q * 2048 + t * 8) = *(const u16x8*)(src + q * 2048 + t * 8);
    __syncthreads();
    f32x4 acc[2][4] = {};
#pragma unroll
    for (int ks = 0; ks < 4; ++ks) {
      int cu = ks * 4 + kg;
      bf16x8 af[2], bfv[4];
#pragma unroll
      for (int i = 0; i < 2; ++i) {
        int row = wr * 32 + i * 16 + colL;
        af[i] = *(bf16x8*)(At + (row * 16 + (cu ^ (row & 7))) * 8);
      }
#pragma unroll
      for (int n = 0; n < 4; ++n) {
        int orow = wc * 64 + n * 16 + colL;
        bfv[n] = *(bf16x8*)(Gt + (orow * 16 + (cu ^ (orow & 7))) * 8);
      }
#pragma unroll
      for (int i = 0; i < 2; ++i)
#pragma unroll
        for (int n = 0; n < 4; ++n)
          acc[i][n] = __builtin_amdgcn_mfma_f32_16x16x32_bf16(bfv[n], af[i], acc[i][n], 0, 0, 0);
    }
    float* ob = oute + ((size_t)bl * 512 + r0) * 128;
#pragma unroll
    for (int i = 0; i < 2; ++i) {
      int m = wr * 32 + i * 16 + colL;
      const float* pmp = Pm + ((size_t)b * 512 + r0 + m) * 128;
      float* orow = ob + (size_t)m * 128;
#pragma unroll
      for (int n = 0; n < 4; ++n) {
        int oc = wc * 64 + n * 16 + kg * 4;
        f32x4 pm4 = *(const f32x4*)(pmp + oc);
        f32x4 o4;
#pragma unroll
        for (int r = 0; r < 4; ++r) o4[r] = acc[i][n][r] + plv4[n][r] + pm4[r];
        *(f32x4*)(orow + oc) = o4;
      }
    }
    __syncthreads();
  }
}

// ---------------------------------------------------------------------------
// Ed: fallback direct-f32 edge GEMM (R6 version).
// ---------------------------------------------------------------------------
__global__ __launch_bounds__(256) void kEd(const float* edge, const u16* Gb,
                                           const float* Pl, const float* Pm, float* oute) {
  __shared__ u16 Gt[16384];
  __shared__ u16 At[8192];
  const int tile = blockIdx.x;
  const int bl = tile >> 2;
  const int b = bl >> 9;
  const int q0 = (tile & 3) * 128;
  const int t = threadIdx.x, lane = t & 63, w = t >> 6;
#pragma unroll
  for (int i2 = 0; i2 < 8; ++i2) {
    int u = i2 * 256 + t;
    int row = u >> 4, cu = u & 15;
    *(u16x8*)(Gt + (row * 16 + (cu ^ (row & 7))) * 8) = *(const u16x8*)(Gb + u * 8);
  }
  const int wr = w >> 1, wc = w & 1;
  const int colL = lane & 15, kg = lane >> 4;
  const float* plp = Pl + (size_t)bl * 128;
  f32x4 plv4[4];
#pragma unroll
  for (int n = 0; n < 4; ++n) plv4[n] = *(const f32x4*)(plp + wc * 64 + n * 16 + kg * 4);
  const int arow = t >> 2, aseg = t & 3;

  for (int sub = 0; sub < 2; ++sub) {
    const int r0 = q0 + sub * 64;
    {
      const float* p = edge + ((size_t)bl * 512 + r0 + arow) * 128 + aseg * 32;
      f32x4 v[8];
#pragma unroll
      for (int q = 0; q < 8; ++q) v[q] = *(const f32x4*)(p + q * 4);
#pragma unroll
      for (int jj = 0; jj < 4; ++jj) {
        u16x8 a8;
#pragma unroll
        for (int j2 = 0; j2 < 4; ++j2) {
          a8[j2]     = f2b(v[2 * jj][j2]);
          a8[4 + j2] = f2b(v[2 * jj + 1][j2]);
        }
        int cu = aseg * 4 + jj;
        *(u16x8*)(At + (arow * 16 + (cu ^ (arow & 7))) * 8) = a8;
      }
    }
    __syncthreads();
    f32x4 acc[2][4] = {};
#pragma unroll
    for (int ks = 0; ks < 4; ++ks) {
      int cu = ks * 4 + kg;
      bf16x8 af[2], bfv[4];
#pragma unroll
      for (int i = 0; i < 2; ++i) {
        int row = wr * 32 + i * 16 + colL;
        af[i] = *(bf16x8*)(At + (row * 16 + (cu ^ (row & 7))) * 8);
      }
#pragma unroll
      for (int n = 0; n < 4; ++n) {
        int orow = wc * 64 + n * 16 + colL;
        bfv[n] = *(bf16x8*)(Gt + (orow * 16 + (cu ^ (orow & 7))) * 8);
      }
#pragma unroll
      for (int i = 0; i < 2; ++i)
#pragma unroll
        for (int n = 0; n < 4; ++n)
          acc[i][n] = __builtin_amdgcn_mfma_f32_16x16x32_bf16(bfv[n], af[i], acc[i][n], 0, 0, 0);
    }
    float* ob = oute + ((size_t)bl * 512 + r0) * 128;
#pragma unroll
    for (int i = 0; i < 2; ++i) {
      int m = wr * 32 + i * 16 + colL;
      const float* pmp = Pm + ((size_t)b * 512 + r0 + m) * 128;
      float* orow = ob + (size_t)m * 128;
#pragma unroll
      for (int n = 0; n < 4; ++n) {
        int oc = wc * 64 + n * 16 + kg * 4;
        f32x4 pm4 = *(const f32x4*)(pmp + oc);
        f32x4 o4;
#pragma unroll
        for (int r = 0; r < 4; ++r) o4[r] = acc[i][n][r] + plv4[n][r] + pm4[r];
        *(f32x4*)(orow + oc) = o4;
      }
    }
    __syncthreads();
  }
}

extern "C" void kernel_launch(void* const* d_in, const int* in_sizes, int n_in,
                              void* d_out, int out_size, void* d_ws, size_t ws_size,
                              hipStream_t stream) {
  (void)in_sizes; (void)n_in; (void)out_size;
  const float* node   = (const float*)d_in[0];
  const float* edge   = (const float*)d_in[1];
  const float* diff   = (const float*)d_in[2];
  const float* Wn_w   = (const float*)d_in[3];
  const float* Wn_b   = (const float*)d_in[4];
  const float* We_w   = (const float*)d_in[5];
  const float* We_b   = (const float*)d_in[6];
  const float* Wd_w   = (const float*)d_in[7];
  const float* Wd_b   = (const float*)d_in[8];
  const float* Wh_w   = (const float*)d_in[9];
  const float* Wh_b   = (const float*)d_in[10];
  const float* attn   = (const float*)d_in[11];
  const float* outn_w = (const float*)d_in[12];
  const float* outn_b = (const float*)d_in[13];
  const float* Wn2_w  = (const float*)d_in[14];
  const float* Wn2_b  = (const float*)d_in[15];
  const float* We2_w  = (const float*)d_in[16];
  const float* We2_b  = (const float*)d_in[17];
  const float* Wd2_w  = (const float*)d_in[18];
  const float* Wd2_b  = (const float*)d_in[19];
  const float* edge_w = (const float*)d_in[20];
  const float* edge_b = (const float*)d_in[21];
  const float* oute_w = (const float*)d_in[22];
  const float* oute_b = (const float*)d_in[23];

  float* out0 = (float*)d_out;           // new_node f32 (524288)
  float* out1 = out0 + 524288;           // new_edge f32

  float* f = (float*)d_ws;
  size_t off = 0;
  auto alloc = [&](size_t n) { float* p = f + off; off += (n + 7) & ~(size_t)7; return p; };
  float* npj    = alloc(524288);
  float* nwh    = alloc(524288);
  float* srow   = alloc(8192);
  float* scol   = alloc(8192);
  float* sconst = alloc(8);
  float* cbe    = alloc(128);
  float* Mfull  = alloc(16384);
  float* nnp    = alloc(524288);
  float* Pl     = alloc(131072);
  float* Pm     = alloc(131072);
  u16* vb = (u16*)(f + off); off += 1024;   // 2048 u16
  u16* Gb = (u16*)(f + off); off += 8192;   // 16384 u16
  // bf16 edge cache: 2*512*512*128 u16 = 134.2 MB
  const size_t abf_elems = (size_t)2 * 512 * 512 * 128;
  bool cache = ws_size >= off * 4 + abf_elems * 2 + 256;
  u16* Abf = cache ? (u16*)(f + off) : nullptr;

  hipLaunchKernelGGL(kW1, dim3(73), dim3(256), 0, stream,
                     We_w, We_b, attn, We2_w, We2_b, edge_w, edge_b, Mfull, vb, cbe, sconst);
  hipLaunchKernelGGL(kW2, dim3(64), dim3(256), 0, stream, oute_w, Mfull, Gb);
  hipLaunchKernelGGL(kN1, dim3(512), dim3(256), 0, stream,
                     node, diff, Wn_w, Wn_b, Wd_w, Wd_b, Wh_w, Wh_b, attn, sconst,
                     npj, nwh, srow, scol);
  hipLaunchKernelGGL(kA, dim3(1024), dim3(256), 0, stream,
                     edge, npj, nwh, srow, scol, vb, nnp, Abf);
  hipLaunchKernelGGL(kN234, dim3(512), dim3(256), 0, stream,
                     nnp, diff, outn_w, outn_b, Wn2_w, Wn2_b, Wd2_w, Wd2_b,
                     edge_w, cbe, oute_w, oute_b, out0, Pl, Pm);
  if (cache)
    hipLaunchKernelGGL(kEc, dim3(4096), dim3(256), 0, stream, Abf, Gb, Pl, Pm, out1);
  else
    hipLaunchKernelGGL(kEd, dim3(4096), dim3(256), 0, stream, edge, Gb, Pl, Pm, out1);
}

// Round 8
// 460.138 us; speedup vs baseline: 1.0313x; 1.0313x over previous
//
#include <hip/hip_runtime.h>
#include <hip/hip_bf16.h>

typedef unsigned short u16;
typedef unsigned short u16x8 __attribute__((ext_vector_type(8)));
typedef __bf16 bf16x8 __attribute__((ext_vector_type(8)));
typedef float f32x4 __attribute__((ext_vector_type(4)));

#define LRS 0.2f

__device__ __forceinline__ u16 f2b(float f) {
  __hip_bfloat16 h = __float2bfloat16(f);
  return __builtin_bit_cast(u16, h);
}

// ---------------------------------------------------------------------------
// R rows (LDS f32, stride K) x W[O][K] f32 -> y[R][O]; KSEG lanes per K.
// ---------------------------------------------------------------------------
template<int K, int O, int KSEG, int R>
__device__ __forceinline__ void gemm_rowsR(const float* xr, const float* W, const float* bias,
                                           float* yl, float* yg, int ygstride) {
  constexpr int KPT = K / KSEG;
  constexpr int OPP = 256 / KSEG;
  const int t = threadIdx.x;
  const int ks = t % KSEG;
  const int oi = t / KSEG;
#pragma unroll
  for (int pass = 0; pass < O / OPP; ++pass) {
    const int o = pass * OPP + oi;
    float a[R];
#pragma unroll
    for (int r = 0; r < R; ++r) a[r] = 0.0f;
    const float* wp = W + (size_t)o * K + ks * KPT;
    const float* xb = xr + ks * KPT;
#pragma unroll 4
    for (int kc = 0; kc < KPT; kc += 4) {
      f32x4 w4 = *(const f32x4*)(wp + kc);
#pragma unroll
      for (int r = 0; r < R; ++r) {
        f32x4 x = *(const f32x4*)(xb + r * K + kc);
#pragma unroll
        for (int j = 0; j < 4; ++j) a[r] += x[j] * w4[j];
      }
    }
#pragma unroll
    for (int d = 1; d < KSEG; d <<= 1)
#pragma unroll
      for (int r = 0; r < R; ++r) a[r] += __shfl_xor(a[r], d, 64);
    if (ks == 0) {
      float bv = bias ? bias[o] : 0.0f;
#pragma unroll
      for (int r = 0; r < R; ++r) {
        float v = a[r] + bv;
        if (yl) yl[r * O + o] = v;
        if (yg) yg[(size_t)r * ygstride + o] = v;
      }
    }
  }
}

// ---------------------------------------------------------------------------
// W1: fold weights. Mfull[hf][c]; vb[c][16] bf16; cbe; sconst.
// ---------------------------------------------------------------------------
__global__ __launch_bounds__(256) void kW1(const float* We_w, const float* We_b, const float* attn,
                                           const float* We2_w, const float* We2_b,
                                           const float* edge_w, const float* edge_b,
                                           float* Mfull, u16* vb, float* cbe, float* sconst) {
  int gid = blockIdx.x * 256 + threadIdx.x;
  if (gid < 16384) {
    int hf = gid >> 7, c = gid & 127;
    int h = hf >> 4, fo = hf & 15;
    float s = 0;
    for (int e = 0; e < 16; ++e)
      s += edge_w[fo * 176 + e] * We2_w[(h * 16 + e) * 128 + c];
    Mfull[hf * 128 + c] = s;
  } else if (gid < 16384 + 2048) {
    int idx = gid - 16384;
    int c = idx >> 4, hc = idx & 15;
    float s = 0;
    if (hc < 8)
      for (int e = 0; e < 16; ++e)
        s += We_w[(hc * 16 + e) * 128 + c] * attn[128 + e];
    vb[c * 16 + hc] = f2b(s);
  } else if (gid < 18432 + 128) {
    int hf = gid - 18432;
    int h = hf >> 4, fo = hf & 15;
    float s = edge_b[fo];
    for (int e = 0; e < 16; ++e)
      s += We2_b[h * 16 + e] * edge_w[fo * 176 + e];
    cbe[hf] = s;
  } else if (gid < 18560 + 8) {
    int h = gid - 18560;
    float s = 0;
    for (int e = 0; e < 16; ++e)
      s += We_b[h * 16 + e] * attn[128 + e];
    sconst[h] = s;
  }
}

// W2: G[o][c] bf16
__global__ __launch_bounds__(256) void kW2(const float* oute_w, const float* Mfull, u16* Gb) {
  int gid = blockIdx.x * 256 + threadIdx.x;
  int o = gid >> 7, c = gid & 127;
  float s = 0;
  for (int k = 0; k < 128; ++k)
    s += oute_w[o * 128 + k] * Mfull[k * 128 + c];
  Gb[o * 128 + c] = f2b(s);
}

// ---------------------------------------------------------------------------
// N1: per 2 node-rows (grid 512): npj, dpj, node_wh, srow, scol
// ---------------------------------------------------------------------------
__global__ __launch_bounds__(256) void kN1(const float* node, const float* diff,
                                           const float* Wn_w, const float* Wn_b,
                                           const float* Wd_w, const float* Wd_b,
                                           const float* Wh_w, const float* Wh_b,
                                           const float* attn, const float* sconst,
                                           float* npj_g, float* nwh_g,
                                           float* srow_g, float* scol_g) {
  __shared__ float nrow[2 * 512], npjl[2 * 512], drow[2 * 128], dpjl[2 * 128];
  const int t = threadIdx.x;
  const int r0 = blockIdx.x * 2;
  *(f32x4*)&nrow[t * 4] = *(const f32x4*)(node + (size_t)r0 * 512 + t * 4);
  if (t < 64) *(f32x4*)&drow[t * 4] = *(const f32x4*)(diff + (size_t)r0 * 128 + t * 4);
  __syncthreads();
  gemm_rowsR<512, 512, 4, 2>(nrow, Wn_w, Wn_b, npjl, npj_g + (size_t)r0 * 512, 512);
  gemm_rowsR<128, 128, 4, 2>(drow, Wd_w, Wd_b, dpjl, nullptr, 0);
  __syncthreads();
  {
    int d = t & 63, hh = t >> 6;
#pragma unroll
    for (int hi = 0; hi < 2; ++hi) {
      int h = hh + hi * 4;
      float wb = Wh_b[d];
      float acc[2] = {wb, wb};
      for (int k = 0; k < 64; ++k) {
        float w = Wh_w[d * 64 + k];
#pragma unroll
        for (int r = 0; r < 2; ++r) acc[r] += npjl[r * 512 + h * 64 + k] * w;
      }
#pragma unroll
      for (int r = 0; r < 2; ++r) nwh_g[(size_t)(r0 + r) * 512 + h * 64 + d] = acc[r];
    }
  }
  if (t < 16) {
    int r = t >> 3, h = t & 7;
    float shi = 0, shj = 0, sdi = 0, sdj = 0;
    for (int d = 0; d < 64; ++d) {
      float x = npjl[r * 512 + h * 64 + d];
      shi += x * attn[d];
      shj += x * attn[64 + d];
    }
    for (int e = 0; e < 16; ++e) {
      float x = dpjl[r * 128 + h * 16 + e];
      sdi += x * attn[144 + e];
      sdj += x * attn[160 + e];
    }
    srow_g[(r0 + r) * 8 + h] = shi + sdi + sconst[h];
    scol_g[(r0 + r) * 8 + h] = shj + sdj;
  }
}

// ---------------------------------------------------------------------------
// A: per (b,l) block (grid 1024). Streams edge once: scores via MFMA with
// register-prefetch + LDS dbuf; writes LINEAR bf16 cache; softmax; writes
// unnormalized P bf16 [b][h][l][m] + 1/denominator. NO agg here.
// ---------------------------------------------------------------------------
__global__ __launch_bounds__(256) void kA(const float* edge, const float* srow, const float* scol,
                                          const u16* vb, u16* P, float* invs, u16* abf) {
  __shared__ u16 At[2][8192];           // 2 x 16 KB, swizzled
  __shared__ float smx[512 * 9];        // scores / probs
  __shared__ float red[256];
  __shared__ float mxh8[8];
  const int bl = blockIdx.x;
  const int b = bl >> 9, l = bl & 511;
  const int t = threadIdx.x;
  const int lane = t & 63, w = t >> 6;
  const int colL = lane & 15, kg = lane >> 4;
  const int h = t & 7, seg = t >> 3;

  bf16x8 bfr[4];
#pragma unroll
  for (int ks = 0; ks < 4; ++ks) {
    u16x8 u;
#pragma unroll
    for (int j = 0; j < 8; ++j) u[j] = vb[(ks * 32 + kg * 8 + j) * 16 + colL];
    bfr[ks] = __builtin_bit_cast(bf16x8, u);
  }

  const float* eb = edge + (size_t)bl * 65536;
  f32x4 va[8], vn[8];
#pragma unroll
  for (int j = 0; j < 4; ++j) {
    va[2 * j]     = *(const f32x4*)(eb + j * 2048 + t * 8);
    va[2 * j + 1] = *(const f32x4*)(eb + j * 2048 + t * 8 + 4);
  }
  for (int tl = 0; tl < 8; ++tl) {
    u16* cdst = abf ? abf + ((size_t)bl * 8 + tl) * 8192 : nullptr;
    u16* lbuf = At[tl & 1];
#pragma unroll
    for (int j = 0; j < 4; ++j) {
      u16x8 a8;
#pragma unroll
      for (int q = 0; q < 4; ++q) { a8[q] = f2b(va[2 * j][q]); a8[4 + q] = f2b(va[2 * j + 1][q]); }
      int c = j * 256 + t;
      int row = c >> 4, cu = c & 15;
      *(u16x8*)(lbuf + (row * 16 + (cu ^ (row & 7))) * 8) = a8;
      if (cdst) *(u16x8*)(cdst + c * 8) = a8;   // LINEAR global image
    }
    if (tl < 7) {
      const float* nb2 = eb + (tl + 1) * 8192;
#pragma unroll
      for (int j = 0; j < 4; ++j) {
        vn[2 * j]     = *(const f32x4*)(nb2 + j * 2048 + t * 8);
        vn[2 * j + 1] = *(const f32x4*)(nb2 + j * 2048 + t * 8 + 4);
      }
    }
    __syncthreads();
    f32x4 acc = {0, 0, 0, 0};
#pragma unroll
    for (int ks = 0; ks < 4; ++ks) {
      int cu = ks * 4 + kg;
      int lrow = w * 16 + colL;
      bf16x8 af = *(bf16x8*)(lbuf + (lrow * 16 + (cu ^ (lrow & 7))) * 8);
      acc = __builtin_amdgcn_mfma_f32_16x16x32_bf16(af, bfr[ks], acc, 0, 0, 0);
    }
    if (colL < 8) {
#pragma unroll
      for (int r = 0; r < 4; ++r)
        smx[(tl * 64 + w * 16 + kg * 4 + r) * 9 + colL] = acc[r];
    }
#pragma unroll
    for (int q = 0; q < 8; ++q) va[q] = vn[q];
  }
  __syncthreads();

  // softmax pass 1
  const float srh2 = srow[(size_t)bl * 8 + h];
  float mx = -__builtin_inff();
#pragma unroll 4
  for (int i = 0; i < 16; ++i) {
    int m = seg * 16 + i;
    float sv = smx[m * 9 + h] + srh2 + scol[((size_t)b * 512 + m) * 8 + h];
    sv = (m == l) ? -__builtin_inff() : (sv >= 0.0f ? sv : LRS * sv);
    smx[m * 9 + h] = sv;
    mx = fmaxf(mx, sv);
  }
  red[t] = mx;
  __syncthreads();
  if (t < 8) {
    float m2 = -__builtin_inff();
    for (int sg = 0; sg < 32; ++sg) m2 = fmaxf(m2, red[sg * 8 + t]);
    mxh8[t] = m2;
  }
  __syncthreads();
  float mh = mxh8[h];
  float smv = 0;
#pragma unroll 4
  for (int i = 0; i < 16; ++i) {
    int m = seg * 16 + i;
    float p = __expf(smx[m * 9 + h] - mh);
    smx[m * 9 + h] = p;
    smv += p;
  }
  red[t] = smv;
  __syncthreads();
  if (t < 8) {
    float s2 = 0;
    for (int sg = 0; sg < 32; ++sg) s2 += red[sg * 8 + t];
    invs[(size_t)bl * 8 + t] = 1.0f / s2;
  }
  __syncthreads();
  // write P bf16 [b][h][l][m]
#pragma unroll
  for (int k = 0; k < 2; ++k) {
    int c = k * 256 + t;
    int hp = c >> 6, mb = (c & 63) * 8;
    u16x8 pk;
#pragma unroll
    for (int j = 0; j < 8; ++j) pk[j] = f2b(smx[(mb + j) * 9 + hp]);
    *(u16x8*)(P + (((size_t)b * 8 + hp) * 512 + l) * 512 + mb) = pk;
  }
}

// ---------------------------------------------------------------------------
// Agg: per (b,h,ltile64): agg[l][d] = sum_m P[b,h,l,m]*nwh[b,m,h*64+d]
// Tiled MFMA GEMM K=512; epilogue: *inv, lrelu, +npj -> nnp.
// ---------------------------------------------------------------------------
__global__ __launch_bounds__(256) void kAgg(const u16* P, const float* nwh, const float* npj,
                                            const float* invs, float* nnp) {
  __shared__ u16 Pt[8192];   // [64 l][128 m] swizzled
  __shared__ u16 Vt[8192];   // [64 d][128 m] swizzled (transposed nwh)
  const int bid = blockIdx.x;
  const int lt = bid & 7, h = (bid >> 3) & 7, b = bid >> 6;
  const int l0 = lt * 64;
  const int t = threadIdx.x;
  const int lane = t & 63, w = t >> 6;
  const int colL = lane & 15, kg = lane >> 4;

  f32x4 acc[4] = {};
  for (int mc = 0; mc < 4; ++mc) {
    // stage P tile
#pragma unroll
    for (int q = 0; q < 4; ++q) {
      int c = q * 256 + t;
      int row = c >> 4, cu = c & 15;
      u16x8 a8 = *(const u16x8*)(P + (((size_t)b * 8 + h) * 512 + l0 + row) * 512 + mc * 128 + cu * 8);
      *(u16x8*)(Pt + (row * 16 + (cu ^ (row & 7))) * 8) = a8;
    }
    // stage nwh transposed
#pragma unroll
    for (int q = 0; q < 8; ++q) {
      int c = q * 256 + t;
      int m = c >> 4, d4 = (c & 15) * 4;
      f32x4 v = *(const f32x4*)(nwh + ((size_t)b * 512 + mc * 128 + m) * 512 + h * 64 + d4);
#pragma unroll
      for (int j = 0; j < 4; ++j) {
        int d = d4 + j;
        Vt[(d * 16 + ((m >> 3) ^ (d & 7))) * 8 + (m & 7)] = f2b(v[j]);
      }
    }
    __syncthreads();
#pragma unroll
    for (int kc = 0; kc < 4; ++kc) {
      int cu = kc * 4 + kg;
      int prow = w * 16 + colL;
      bf16x8 af = *(bf16x8*)(Pt + (prow * 16 + (cu ^ (prow & 7))) * 8);
#pragma unroll
      for (int n = 0; n < 4; ++n) {
        int d = n * 16 + colL;
        bf16x8 bf = *(bf16x8*)(Vt + (d * 16 + (cu ^ (d & 7))) * 8);
        acc[n] = __builtin_amdgcn_mfma_f32_16x16x32_bf16(af, bf, acc[n], 0, 0, 0);
      }
    }
    __syncthreads();
  }
  // epilogue
#pragma unroll
  for (int r = 0; r < 4; ++r) {
    int l = l0 + w * 16 + kg * 4 + r;
    float iv = invs[((size_t)b * 512 + l) * 8 + h];
#pragma unroll
    for (int n = 0; n < 4; ++n) {
      int o = h * 64 + n * 16 + colL;
      size_t idx = ((size_t)b * 512 + l) * 512 + o;
      float a = acc[n][r] * iv;
      a = a >= 0.0f ? a : LRS * a;
      nnp[idx] = npj[idx] + a;
    }
  }
}

// ---------------------------------------------------------------------------
// N234 (fused, 2 rows/block, grid 512): nnp -> out0 -> np2/dp2 -> R -> Pl/Pm
// ---------------------------------------------------------------------------
__global__ __launch_bounds__(256) void kN234(const float* nnp, const float* diff,
                                             const float* outn_w, const float* outn_b,
                                             const float* Wn2_w, const float* Wn2_b,
                                             const float* Wd2_w, const float* Wd2_b,
                                             const float* edge_w, const float* cbe,
                                             const float* oute_w, const float* oute_b,
                                             float* out0, float* Pl, float* Pm) {
  __shared__ float xr[2 * 512], o0l[2 * 512], np2l[2 * 512], dr[2 * 128], dp2l[2 * 128];
  __shared__ float Rls[2 * 128], Rms[2 * 128];
  const int t = threadIdx.x;
  const int r0 = blockIdx.x * 2;
  *(f32x4*)&xr[t * 4] = *(const f32x4*)(nnp + (size_t)r0 * 512 + t * 4);
  if (t < 64) *(f32x4*)&dr[t * 4] = *(const f32x4*)(diff + (size_t)r0 * 128 + t * 4);
  __syncthreads();
  gemm_rowsR<512, 512, 4, 2>(xr, outn_w, outn_b, o0l, out0 + (size_t)r0 * 512, 512);
  gemm_rowsR<128, 128, 4, 2>(dr, Wd2_w, Wd2_b, dp2l, nullptr, 0);
  __syncthreads();
  gemm_rowsR<512, 512, 4, 2>(o0l, Wn2_w, Wn2_b, np2l, nullptr, 0);
  __syncthreads();
  {
    int hf = t & 127, which = t >> 7;
    int h = hf >> 4, fo = hf & 15;
    const float* wh = edge_w + fo * 176 + 16 + which * 64;   // W_hi / W_hj
    const float* wd = edge_w + fo * 176 + 144 + which * 16;  // W_di / W_dj
    float add = which ? 0.0f : cbe[hf];
    float* dst = which ? Rms : Rls;
#pragma unroll
    for (int r = 0; r < 2; ++r) {
      float a = add;
      for (int d = 0; d < 64; ++d) a += np2l[r * 512 + h * 64 + d] * wh[d];
      for (int e = 0; e < 16; ++e) a += dp2l[r * 128 + h * 16 + e] * wd[e];
      dst[r * 128 + hf] = a;
    }
  }
  __syncthreads();
  gemm_rowsR<128, 128, 4, 2>(Rls, oute_w, oute_b, nullptr, Pl + (size_t)r0 * 128, 128);
  gemm_rowsR<128, 128, 4, 2>(Rms, oute_w, nullptr, nullptr, Pm + (size_t)r0 * 128, 128);
}

// ---------------------------------------------------------------------------
// Ec: cached-bf16 edge GEMM; linear cache read, swizzle on LDS write.
// ---------------------------------------------------------------------------
__global__ __launch_bounds__(256) void kEc(const u16* Abf, const u16* Gb,
                                           const float* Pl, const float* Pm, float* oute) {
  __shared__ u16 Gt[16384];
  __shared__ u16 At[8192];
  const int tile = blockIdx.x;
  const int bl = tile >> 2;
  const int b = bl >> 9;
  const int q0 = (tile & 3) * 128;
  const int t = threadIdx.x, lane = t & 63, w = t >> 6;
#pragma unroll
  for (int i2 = 0; i2 < 8; ++i2) {
    int u = i2 * 256 + t;
    int row = u >> 4, cu = u & 15;
    *(u16x8*)(Gt + (row * 16 + (cu ^ (row & 7))) * 8) = *(const u16x8*)(Gb + u * 8);
  }
  const int wr = w >> 1, wc = w & 1;
  const int colL = lane & 15, kg = lane >> 4;
  const float* plp = Pl + (size_t)bl * 128;
  f32x4 plv4[4];
#pragma unroll
  for (int n = 0; n < 4; ++n) plv4[n] = *(const f32x4*)(plp + wc * 64 + n * 16 + kg * 4);

  for (int sub = 0; sub < 2; ++sub) {
    const int r0 = q0 + sub * 64;
    const int gs = (tile & 3) * 2 + sub;
    const u16* src = Abf + ((size_t)bl * 8 + gs) * 8192;
#pragma unroll
    for (int q = 0; q < 4; ++q) {
      int c = q * 256 + t;
      u16x8 a8 = *(const u16x8*)(src + c * 8);
      int row = c >> 4, cu = c & 15;
      *(u16x8*)(At + (row * 16 + (cu ^ (row & 7))) * 8) = a8;
    }
    __syncthreads();
    f32x4 acc[2][4] = {};
#pragma unroll
    for (int ks = 0; ks < 4; ++ks) {
      int cu = ks * 4 + kg;
      bf16x8 af[2], bfv[4];
#pragma unroll
      for (int i = 0; i < 2; ++i) {
        int row = wr * 32 + i * 16 + colL;
        af[i] = *(bf16x8*)(At + (row * 16 + (cu ^ (row & 7))) * 8);
      }
#pragma unroll
      for (int n = 0; n < 4; ++n) {
        int orow = wc * 64 + n * 16 + colL;
        bfv[n] = *(bf16x8*)(Gt + (orow * 16 + (cu ^ (orow & 7))) * 8);
      }
#pragma unroll
      for (int i = 0; i < 2; ++i)
#pragma unroll
        for (int n = 0; n < 4; ++n)
          acc[i][n] = __builtin_amdgcn_mfma_f32_16x16x32_bf16(bfv[n], af[i], acc[i][n], 0, 0, 0);
    }
    float* ob = oute + ((size_t)bl * 512 + r0) * 128;
#pragma unroll
    for (int i = 0; i < 2; ++i) {
      int m = wr * 32 + i * 16 + colL;
      const float* pmp = Pm + ((size_t)b * 512 + r0 + m) * 128;
      float* orow = ob + (size_t)m * 128;
#pragma unroll
      for (int n = 0; n < 4; ++n) {
        int oc = wc * 64 + n * 16 + kg * 4;
        f32x4 pm4 = *(const f32x4*)(pmp + oc);
        f32x4 o4;
#pragma unroll
        for (int r = 0; r < 4; ++r) o4[r] = acc[i][n][r] + plv4[n][r] + pm4[r];
        *(f32x4*)(orow + oc) = o4;
      }
    }
    __syncthreads();
  }
}

// ---------------------------------------------------------------------------
// Ed: fallback direct-f32 edge GEMM.
// ---------------------------------------------------------------------------
__global__ __launch_bounds__(256) void kEd(const float* edge, const u16* Gb,
                                           const float* Pl, const float* Pm, float* oute) {
  __shared__ u16 Gt[16384];
  __shared__ u16 At[8192];
  const int tile = blockIdx.x;
  const int bl = tile >> 2;
  const int b = bl >> 9;
  const int q0 = (tile & 3) * 128;
  const int t = threadIdx.x, lane = t & 63, w = t >> 6;
#pragma unroll
  for (int i2 = 0; i2 < 8; ++i2) {
    int u = i2 * 256 + t;
    int row = u >> 4, cu = u & 15;
    *(u16x8*)(Gt + (row * 16 + (cu ^ (row & 7))) * 8) = *(const u16x8*)(Gb + u * 8);
  }
  const int wr = w >> 1, wc = w & 1;
  const int colL = lane & 15, kg = lane >> 4;
  const float* plp = Pl + (size_t)bl * 128;
  f32x4 plv4[4];
#pragma unroll
  for (int n = 0; n < 4; ++n) plv4[n] = *(const f32x4*)(plp + wc * 64 + n * 16 + kg * 4);
  const int arow = t >> 2, aseg = t & 3;

  for (int sub = 0; sub < 2; ++sub) {
    const int r0 = q0 + sub * 64;
    {
      const float* p = edge + ((size_t)bl * 512 + r0 + arow) * 128 + aseg * 32;
      f32x4 v[8];
#pragma unroll
      for (int q = 0; q < 8; ++q) v[q] = *(const f32x4*)(p + q * 4);
#pragma unroll
      for (int jj = 0; jj < 4; ++jj) {
        u16x8 a8;
#pragma unroll
        for (int j2 = 0; j2 < 4; ++j2) {
          a8[j2]     = f2b(v[2 * jj][j2]);
          a8[4 + j2] = f2b(v[2 * jj + 1][j2]);
        }
        int cu = aseg * 4 + jj;
        *(u16x8*)(At + (arow * 16 + (cu ^ (arow & 7))) * 8) = a8;
      }
    }
    __syncthreads();
    f32x4 acc[2][4] = {};
#pragma unroll
    for (int ks = 0; ks < 4; ++ks) {
      int cu = ks * 4 + kg;
      bf16x8 af[2], bfv[4];
#pragma unroll
      for (int i = 0; i < 2; ++i) {
        int row = wr * 32 + i * 16 + colL;
        af[i] = *(bf16x8*)(At + (row * 16 + (cu ^ (row & 7))) * 8);
      }
#pragma unroll
      for (int n = 0; n < 4; ++n) {
        int orow = wc * 64 + n * 16 + colL;
        bfv[n] = *(bf16x8*)(Gt + (orow * 16 + (cu ^ (orow & 7))) * 8);
      }
#pragma unroll
      for (int i = 0; i < 2; ++i)
#pragma unroll
        for (int n = 0; n < 4; ++n)
          acc[i][n] = __builtin_amdgcn_mfma_f32_16x16x32_bf16(bfv[n], af[i], acc[i][n], 0, 0, 0);
    }
    float* ob = oute + ((size_t)bl * 512 + r0) * 128;
#pragma unroll
    for (int i = 0; i < 2; ++i) {
      int m = wr * 32 + i * 16 + colL;
      const float* pmp = Pm + ((size_t)b * 512 + r0 + m) * 128;
      float* orow = ob + (size_t)m * 128;
#pragma unroll
      for (int n = 0; n < 4; ++n) {
        int oc = wc * 64 + n * 16 + kg * 4;
        f32x4 pm4 = *(const f32x4*)(pmp + oc);
        f32x4 o4;
#pragma unroll
        for (int r = 0; r < 4; ++r) o4[r] = acc[i][n][r] + plv4[n][r] + pm4[r];
        *(f32x4*)(orow + oc) = o4;
      }
    }
    __syncthreads();
  }
}

extern "C" void kernel_launch(void* const* d_in, const int* in_sizes, int n_in,
                              void* d_out, int out_size, void* d_ws, size_t ws_size,
                              hipStream_t stream) {
  (void)in_sizes; (void)n_in; (void)out_size;
  const float* node   = (const float*)d_in[0];
  const float* edge   = (const float*)d_in[1];
  const float* diff   = (const float*)d_in[2];
  const float* Wn_w   = (const float*)d_in[3];
  const float* Wn_b   = (const float*)d_in[4];
  const float* We_w   = (const float*)d_in[5];
  const float* We_b   = (const float*)d_in[6];
  const float* Wd_w   = (const float*)d_in[7];
  const float* Wd_b   = (const float*)d_in[8];
  const float* Wh_w   = (const float*)d_in[9];
  const float* Wh_b   = (const float*)d_in[10];
  const float* attn   = (const float*)d_in[11];
  const float* outn_w = (const float*)d_in[12];
  const float* outn_b = (const float*)d_in[13];
  const float* Wn2_w  = (const float*)d_in[14];
  const float* Wn2_b  = (const float*)d_in[15];
  const float* We2_w  = (const float*)d_in[16];
  const float* We2_b  = (const float*)d_in[17];
  const float* Wd2_w  = (const float*)d_in[18];
  const float* Wd2_b  = (const float*)d_in[19];
  const float* edge_w = (const float*)d_in[20];
  const float* edge_b = (const float*)d_in[21];
  const float* oute_w = (const float*)d_in[22];
  const float* oute_b = (const float*)d_in[23];

  float* out0 = (float*)d_out;           // new_node f32 (524288)
  float* out1 = out0 + 524288;           // new_edge f32

  float* f = (float*)d_ws;
  size_t off = 0;
  auto alloc = [&](size_t n) { float* p = f + off; off += (n + 7) & ~(size_t)7; return p; };
  float* npj    = alloc(524288);
  float* nwh    = alloc(524288);
  float* srow   = alloc(8192);
  float* scol   = alloc(8192);
  float* sconst = alloc(8);
  float* cbe    = alloc(128);
  float* Mfull  = alloc(16384);
  float* nnp    = alloc(524288);
  float* Pl     = alloc(131072);
  float* Pm     = alloc(131072);
  float* invs   = alloc(8192);
  u16* vb = (u16*)(f + off); off += 1024;    // 2048 u16
  u16* Gb = (u16*)(f + off); off += 8192;    // 16384 u16
  u16* P  = (u16*)(f + off); off += 2097152; // 4.19M u16 (8.4 MB)
  const size_t abf_elems = (size_t)2 * 512 * 512 * 128;
  bool cache = ws_size >= off * 4 + abf_elems * 2 + 256;
  u16* Abf = cache ? (u16*)(f + off) : nullptr;

  hipLaunchKernelGGL(kW1, dim3(73), dim3(256), 0, stream,
                     We_w, We_b, attn, We2_w, We2_b, edge_w, edge_b, Mfull, vb, cbe, sconst);
  hipLaunchKernelGGL(kW2, dim3(64), dim3(256), 0, stream, oute_w, Mfull, Gb);
  hipLaunchKernelGGL(kN1, dim3(512), dim3(256), 0, stream,
                     node, diff, Wn_w, Wn_b, Wd_w, Wd_b, Wh_w, Wh_b, attn, sconst,
                     npj, nwh, srow, scol);
  hipLaunchKernelGGL(kA, dim3(1024), dim3(256), 0, stream,
                     edge, srow, scol, vb, P, invs, Abf);
  hipLaunchKernelGGL(kAgg, dim3(128), dim3(256), 0, stream, P, nwh, npj, invs, nnp);
  hipLaunchKernelGGL(kN234, dim3(512), dim3(256), 0, stream,
                     nnp, diff, outn_w, outn_b, Wn2_w, Wn2_b, Wd2_w, Wd2_b,
                     edge_w, cbe, oute_w, oute_b, out0, Pl, Pm);
  if (cache)
    hipLaunchKernelGGL(kEc, dim3(4096), dim3(256), 0, stream, Abf, Gb, Pl, Pm, out1);
  else
    hipLaunchKernelGGL(kEd, dim3(4096), dim3(256), 0, stream, edge, Gb, Pl, Pm, out1);
}